// Round 9
// baseline (1245.659 us; speedup 1.0000x reference)
//
#include <hip/hip_runtime.h>
#include <math.h>

typedef __attribute__((ext_vector_type(8))) short bf16x8;
typedef __attribute__((ext_vector_type(4))) float f32x4;

__device__ __forceinline__ float wsum64(float v) {
#pragma unroll
  for (int d = 32; d > 0; d >>= 1) v += __shfl_xor(v, d, 64);
  return v;
}

__device__ __forceinline__ unsigned short f2bf(float f) {
  unsigned u = __float_as_uint(f);
  u = (u + 0x7FFFu + ((u >> 16) & 1u)) >> 16;
  return (unsigned short)u;
}

__device__ __forceinline__ float bf2f(unsigned short h) {
  return __uint_as_float((unsigned)h << 16);
}

// ---------------- K0: init (chadj extract + zero mean-sums) ----------------
__global__ void k_init(const float* __restrict__ smask, float* __restrict__ chadj,
                       double* __restrict__ sums) {
  int t = threadIdx.x;
  if (t < 4) sums[t] = 0.0;
  if (t < 484) {
    int c1 = t / 22, c2 = t % 22;
    chadj[t] = smask[(size_t)(c1 * 64) * 1408 + (size_t)c2 * 64];
  }
}

// ---------------- A: input GEMM: z (fp32) + 3-term bf16 split + h1-pre ------
// z = x@projw^T (4 heads) -> store fp32 z (for k_node's exact sq) and the
// 3-term bf16 decomposition zb+zbl+zbl2 (x = h+l+m, residual ~2^-27 rel)
// used by k_pass1's MFMA distance GEMM and k_final. zT dropped (unused now).
__global__ __launch_bounds__(256) void k_gemm_in(
    const float* __restrict__ x, const float* __restrict__ projw,
    const float* __restrict__ w1, float* __restrict__ z,
    unsigned short* __restrict__ zb, unsigned short* __restrict__ zbl,
    unsigned short* __restrict__ zbl2, float* __restrict__ h1) {
  __shared__ float xs[16][68];
  __shared__ float wsT[16][68];
  int n0 = blockIdx.x * 64;
  int o0 = blockIdx.y * 64;
  int tid = threadIdx.x;
  int tx = tid & 15, ty = tid >> 4;
  float acc[4][4];
#pragma unroll
  for (int i = 0; i < 4; i++)
#pragma unroll
    for (int j = 0; j < 4; j++) acc[i][j] = 0.f;
  for (int kc = 0; kc < 16; kc++) {
#pragma unroll
    for (int rep = 0; rep < 4; rep++) {
      int e = tid + rep * 256;
      int n = e >> 4, k = e & 15;
      xs[k][n] = x[(size_t)(n0 + n) * 256 + kc * 16 + k];
      int row = o0 + n;
      wsT[k][n] = (row < 256) ? projw[(size_t)row * 256 + kc * 16 + k]
                              : w1[(size_t)(row - 256) * 256 + kc * 16 + k];
    }
    __syncthreads();
#pragma unroll
    for (int k = 0; k < 16; k++) {
      float4 a4 = *(const float4*)&xs[k][4 * ty];
      float4 w4 = *(const float4*)&wsT[k][4 * tx];
      float ar[4] = {a4.x, a4.y, a4.z, a4.w};
      float wr[4] = {w4.x, w4.y, w4.z, w4.w};
#pragma unroll
      for (int i = 0; i < 4; i++)
#pragma unroll
        for (int j = 0; j < 4; j++) acc[i][j] = fmaf(ar[i], wr[j], acc[i][j]);
    }
    __syncthreads();
  }
  if (blockIdx.y >= 4) {
#pragma unroll
    for (int i = 0; i < 4; i++) {
      size_t base = (size_t)(n0 + 4 * ty + i) * 128 + (o0 - 256) + 4 * tx;
      float4 t;
      t.x = acc[i][0]; t.y = acc[i][1]; t.z = acc[i][2]; t.w = acc[i][3];
      *(float4*)&h1[base] = t;
    }
  } else {
#pragma unroll
    for (int i = 0; i < 4; i++) {
      size_t base = (size_t)(n0 + 4 * ty + i) * 256 + o0 + 4 * tx;
      float4 t;
      t.x = acc[i][0]; t.y = acc[i][1]; t.z = acc[i][2]; t.w = acc[i][3];
      *(float4*)&z[base] = t;
      unsigned short hh[4], ll[4], mm[4];
#pragma unroll
      for (int j = 0; j < 4; j++) {
        float xv = acc[i][j];
        unsigned short h0 = f2bf(xv);
        float r1 = xv - bf2f(h0);
        unsigned short h1v = f2bf(r1);
        float r2 = r1 - bf2f(h1v);
        unsigned short h2 = f2bf(r2);
        hh[j] = h0; ll[j] = h1v; mm[j] = h2;
      }
      uint2 u2;
      u2.x = (unsigned)hh[0] | ((unsigned)hh[1] << 16);
      u2.y = (unsigned)hh[2] | ((unsigned)hh[3] << 16);
      *(uint2*)(zb + base) = u2;
      u2.x = (unsigned)ll[0] | ((unsigned)ll[1] << 16);
      u2.y = (unsigned)ll[2] | ((unsigned)ll[3] << 16);
      *(uint2*)(zbl + base) = u2;
      u2.x = (unsigned)mm[0] | ((unsigned)mm[1] << 16);
      u2.y = (unsigned)mm[2] | ((unsigned)mm[3] << 16);
      *(uint2*)(zbl2 + base) = u2;
    }
  }
}

// ---------------- B: per-node: sq per head, score (exact gelu), top-p gate --
__global__ __launch_bounds__(256) void k_node(
    const float* __restrict__ x, const float* __restrict__ z,
    const float* __restrict__ h1, const float* __restrict__ gw,
    const float* __restrict__ gb, const float* __restrict__ b1,
    const float* __restrict__ w2, const float* __restrict__ b2v,
    float* __restrict__ sq, float4* __restrict__ wnode) {
  int tid = threadIdx.x;
  int w = tid >> 6, lane = tid & 63;
  int node = blockIdx.x * 4 + w;
  int b = node / 1408, n = node % 1408;
  const float* zr = z + (size_t)node * 256;
  const float* xr = x + (size_t)node * 256;
#pragma unroll
  for (int c = 0; c < 4; c++) {
    float val = zr[c * 64 + lane];
    float s = wsum64(val * val);
    if (lane == 0) sq[(size_t)(b * 4 + c) * 1408 + n] = s;
  }
  float gl[3];
#pragma unroll
  for (int f = 0; f < 3; f++) {
    float p = 0.f;
#pragma unroll
    for (int c = 0; c < 4; c++)
      p = fmaf(xr[c * 64 + lane], gw[f * 256 + c * 64 + lane], p);
    gl[f] = wsum64(p) + gb[f];
  }
  const float* hr = h1 + (size_t)node * 128;
  float ps = 0.f;
#pragma unroll
  for (int c = 0; c < 2; c++) {
    float t = hr[c * 64 + lane] + b1[c * 64 + lane];
    float g = 0.5f * t * (1.f + erff(t * 0.7071067811865475f));
    ps = fmaf(g, w2[c * 64 + lane], ps);
  }
  float sc = wsum64(ps) + b2v[0];
  sc = 1.f / (1.f + expf(-sc));
  float mx = fmaxf(gl[0], fmaxf(gl[1], gl[2]));
  float ex[3];
  float esum = 0.f;
#pragma unroll
  for (int f = 0; f < 3; f++) { ex[f] = expf(gl[f] - mx); esum += ex[f]; }
  float p3[3];
#pragma unroll
  for (int f = 0; f < 3; f++) p3[f] = ex[f] / esum;
  int rk[3];
#pragma unroll
  for (int f = 0; f < 3; f++) {
    int r = 0;
#pragma unroll
    for (int g = 0; g < 3; g++)
      r += ((p3[g] > p3[f]) || (p3[g] == p3[f] && g < f)) ? 1 : 0;
    rk[f] = r;
  }
  float sp[3]; int oi[3];
#pragma unroll
  for (int f = 0; f < 3; f++) { sp[rk[f]] = p3[f]; oi[rk[f]] = f; }
  bool k1 = sp[0] < 0.85f;
  bool k2 = (sp[0] + sp[1]) < 0.85f;
  float wv[3];
  wv[oi[0]] = sp[0];
  wv[oi[1]] = k1 ? sp[1] : 0.f;
  wv[oi[2]] = k2 ? sp[2] : 0.f;
  float inv = 1.f / (wv[0] + wv[1] + wv[2] + 1e-8f);
  if (lane == 0) wnode[node] = make_float4(wv[0] * inv, wv[1] * inv, wv[2] * inv, sc);
}

// ---------------- P1: MFMA distances + exact top-k(211) select -> bitmap ----
// grid (88,16,4); block 256 = 4 waves; wave w owns j-tiles w*22..w*22+21.
// Distance GEMM on the MATRIX pipe: 3-term bf16 split (z=h+l+m), 6 product
// classes x 2 K-halves = 12 mfma_16x16x32 per 16x16 tile; d^2 noise ~fp32-
// chain-class (~1e-6 rel), same class as the fp32-vs-JAX difference that
// already doesn't flip selections. Phase 1: hist fill (+ssum). Phase 2:
// deterministic bit-identical recompute -> provisional key<tb bits (ballot)
// into LDS bitmap + (d,j) boundary candidates. Rank -> T; boundary atomicOr;
// single bitmap writeout. Output lane map (verified via k_final): row =
// (lane>>4)*4+reg, col = lane&15.
__global__ __launch_bounds__(256, 2) void k_pass1(
    const unsigned short* __restrict__ zb, const unsigned short* __restrict__ zbl,
    const unsigned short* __restrict__ zbl2, const float* __restrict__ sq,
    unsigned* __restrict__ bm, double* __restrict__ sums) {
  __shared__ unsigned hist[8][528];   // rows 2r,2r+1 packed u16; idx = key+(key>>6)
  __shared__ float candD[16][128];
  __shared__ unsigned short candJ[16][128];
  __shared__ unsigned candCnt[16];
  __shared__ int tbinS[16], rstarS[16];
  __shared__ float TS[16];
  __shared__ unsigned bmL[16][44];
  __shared__ float srowL[16];
  int b = blockIdx.y, h = blockIdx.z;
  int i0 = blockIdx.x * 16;
  int tid = threadIdx.x, w = tid >> 6, lane = tid & 63;
  int quad = lane >> 4, l15 = lane & 15;
  const float* sqh = sq + (size_t)(b * 4 + h) * 1408;
  {
    unsigned* hf = &hist[0][0];
    for (int u = tid; u < 8 * 528; u += 256) hf[u] = 0u;
  }
  if (tid < 16) { candCnt[tid] = 0u; srowL[tid] = sqh[i0 + tid]; }
  __syncthreads();

  // A fragments (rows i0..i0+15), 3 split terms x 2 K-halves
  size_t abase = ((size_t)(b * 1408 + i0 + l15)) * 256 + h * 64;
  bf16x8 ah[2], al[2], am[2];
#pragma unroll
  for (int k0 = 0; k0 < 2; k0++) {
    ah[k0] = *(const bf16x8*)(zb + abase + k0 * 32 + quad * 8);
    al[k0] = *(const bf16x8*)(zbl + abase + k0 * 32 + quad * 8);
    am[k0] = *(const bf16x8*)(zbl2 + abase + k0 * 32 + quad * 8);
  }

  auto tdot = [&](int tile) -> f32x4 {
    size_t jb = ((size_t)(b * 1408 + tile * 16 + l15)) * 256 + h * 64;
    bf16x8 bh0 = *(const bf16x8*)(zb + jb + quad * 8);
    bf16x8 bh1 = *(const bf16x8*)(zb + jb + 32 + quad * 8);
    bf16x8 bl0 = *(const bf16x8*)(zbl + jb + quad * 8);
    bf16x8 bl1 = *(const bf16x8*)(zbl + jb + 32 + quad * 8);
    bf16x8 bm0 = *(const bf16x8*)(zbl2 + jb + quad * 8);
    bf16x8 bm1 = *(const bf16x8*)(zbl2 + jb + 32 + quad * 8);
    f32x4 a = {0.f, 0.f, 0.f, 0.f};
    a = __builtin_amdgcn_mfma_f32_16x16x32_bf16(ah[0], bh0, a, 0, 0, 0);
    a = __builtin_amdgcn_mfma_f32_16x16x32_bf16(ah[1], bh1, a, 0, 0, 0);
    a = __builtin_amdgcn_mfma_f32_16x16x32_bf16(ah[0], bl0, a, 0, 0, 0);
    a = __builtin_amdgcn_mfma_f32_16x16x32_bf16(ah[1], bl1, a, 0, 0, 0);
    a = __builtin_amdgcn_mfma_f32_16x16x32_bf16(al[0], bh0, a, 0, 0, 0);
    a = __builtin_amdgcn_mfma_f32_16x16x32_bf16(al[1], bh1, a, 0, 0, 0);
    a = __builtin_amdgcn_mfma_f32_16x16x32_bf16(al[0], bl0, a, 0, 0, 0);
    a = __builtin_amdgcn_mfma_f32_16x16x32_bf16(al[1], bl1, a, 0, 0, 0);
    a = __builtin_amdgcn_mfma_f32_16x16x32_bf16(ah[0], bm0, a, 0, 0, 0);
    a = __builtin_amdgcn_mfma_f32_16x16x32_bf16(ah[1], bm1, a, 0, 0, 0);
    a = __builtin_amdgcn_mfma_f32_16x16x32_bf16(am[0], bh0, a, 0, 0, 0);
    a = __builtin_amdgcn_mfma_f32_16x16x32_bf16(am[1], bh1, a, 0, 0, 0);
    return a;
  };

  float ssum = 0.f;
  // ---- phase 1: hist fill + ssum ----
#pragma unroll 1
  for (int t = 0; t < 22; t++) {
    int tile = w * 22 + t;
    f32x4 acc = tdot(tile);
    float sqjv = sqh[tile * 16 + l15];
#pragma unroll
    for (int reg = 0; reg < 4; reg++) {
      int row = quad * 4 + reg;
      float d = srowL[row] + sqjv - 2.f * acc[reg];
      d = fmaxf(d, 0.f);
      ssum += sqrtf(d);
      unsigned key = (unsigned)fminf(d * 4.0f, 511.0f);
      atomicAdd(&hist[row >> 1][key + (key >> 6)], 1u << ((row & 1) * 16));
    }
  }
  __syncthreads();

  // ---- scan: wave w handles rows 4w..4w+3 ----
#pragma unroll 1
  for (int q = 0; q < 4; q++) {
    int r = 4 * w + q;
    int sh = (r & 1) * 16;
    const unsigned* hrow = hist[r >> 1];
    unsigned partial = 0;
#pragma unroll
    for (int u = 0; u < 8; u++) {
      int bin = 8 * lane + u;
      partial += (hrow[bin + (bin >> 6)] >> sh) & 0xffffu;
    }
    unsigned inc = partial;
#pragma unroll
    for (int d = 1; d < 64; d <<= 1) {
      unsigned u2 = __shfl_up(inc, d, 64);
      if (lane >= d) inc += u2;
    }
    unsigned long long mk = __ballot(inc >= 211u);
    int Ls = __ffsll(mk) - 1;
    unsigned cbefore = (Ls > 0) ? (unsigned)__shfl((int)inc, Ls - 1, 64) : 0u;
    int tb = -1;
    unsigned run = cbefore, cbelow = cbefore;
#pragma unroll
    for (int u = 0; u < 8; u++) {
      int bin = 8 * Ls + u;
      unsigned c = (hrow[bin + (bin >> 6)] >> sh) & 0xffffu;
      if (tb < 0) {
        if (run + c >= 211u) { tb = bin; cbelow = run; }
        run += c;
      }
    }
    if (lane == 0) { tbinS[r] = tb; rstarS[r] = 211 - (int)cbelow; }
  }
  __syncthreads();

  // ---- phase 2: bit-identical recompute -> provisional bits + candidates --
#pragma unroll 1
  for (int t = 0; t < 22; t++) {
    int tile = w * 22 + t;
    f32x4 acc = tdot(tile);
    float sqjv = sqh[tile * 16 + l15];
#pragma unroll
    for (int reg = 0; reg < 4; reg++) {
      int row = quad * 4 + reg;
      float d = srowL[row] + sqjv - 2.f * acc[reg];
      d = fmaxf(d, 0.f);
      unsigned key = (unsigned)fminf(d * 4.0f, 511.0f);
      int tb = tbinS[row];
      unsigned long long bl = __ballot((int)key < tb);
      if (l15 == 0)
        ((unsigned short*)&bmL[row & 3 ? row : row][0])[tile] = 0;  // placeholder no-op avoided below
      if (l15 == 0)
        ((unsigned short*)&bmL[row][0])[tile] = (unsigned short)(bl >> (quad * 16));
      if ((int)key == tb) {
        unsigned id = atomicAdd(&candCnt[row], 1u);
        if (id < 128u) {
          candD[row][id] = d;
          candJ[row][id] = (unsigned short)(tile * 16 + l15);
        }
      }
    }
  }
  __syncthreads();

  // ---- rank within threshold bin: wave w ranks rows 4w..4w+3 ----
#pragma unroll 1
  for (int q = 0; q < 4; q++) {
    int r = 4 * w + q;
    int rstar = rstarS[r];
    unsigned craw = candCnt[r];
    int cnt = (craw > 128u) ? 128 : (int)craw;
    float t2l = INFINITY;
    for (int base = 0; base < cnt; base += 64) {
      int ci = base + lane;
      if (ci < cnt) {
        float xm = candD[r][ci];
        int below = 0, eq = 0;
        for (int m = 0; m < cnt; m++) {
          float y = candD[r][m];
          below += (y < xm) ? 1 : 0;
          eq += (y == xm) ? 1 : 0;
        }
        if (below < rstar && rstar <= below + eq) t2l = fminf(t2l, xm);
      }
    }
#pragma unroll
    for (int dd = 32; dd > 0; dd >>= 1) t2l = fminf(t2l, __shfl_xor(t2l, dd, 64));
    if (lane == 0) TS[r] = t2l;
  }
  __syncthreads();

  // ---- boundary bits: candidates with d <= T ----
#pragma unroll 1
  for (int q = 0; q < 4; q++) {
    int row = 4 * w + q;
    float T = TS[row];
    unsigned craw = candCnt[row];
    int cnt = (craw > 128u) ? 128 : (int)craw;
    for (int ci = lane; ci < cnt; ci += 64) {
      if (candD[row][ci] <= T) {
        int j = candJ[row][ci];
        atomicOr(&bmL[row][j >> 5], 1u << (j & 31));
      }
    }
  }
  __syncthreads();

  // ---- writeout ----
  for (int u = tid; u < 16 * 44; u += 256) {
    int row = u / 44, wd = u % 44;
    bm[((size_t)((h * 16 + b) * 1408 + i0 + row)) * 44 + wd] = bmL[row][wd];
  }
  ssum = wsum64(ssum);
  if (lane == 0) atomicAdd(&sums[h], (double)ssum);
}

// ---------------- E: bf16-MFMA recompute + fused epilogue -> out ------------
__global__ __launch_bounds__(256) void k_final(
    const unsigned short* __restrict__ zb, const float* __restrict__ sq,
    const float4* __restrict__ wnode, const unsigned* __restrict__ bm,
    const double* __restrict__ sums, const float* __restrict__ chadj,
    const float* __restrict__ thrp, float* __restrict__ out) {
  int it = blockIdx.x, jt = blockIdx.y, b = blockIdx.z;
  int tid = threadIdx.x, wv = tid >> 6, lane = tid & 63;
  int quad = lane >> 4, l15 = lane & 15;
  float c2h[4];
#pragma unroll
  for (int h = 0; h < 4; h++) {
    double mu = sums[h] * (1.0 / (16.0 * 1408.0 * 1408.0));
    c2h[h] = (float)(1.0 / (2.0 * mu * mu + 1e-8)) * 1.44269504088896f;
  }
  float thr = thrp[0];
  int ib = it * 64 + wv * 16;
  const unsigned short* za = zb + (size_t)(b * 1408 + ib + l15) * 256;
  bf16x8 af[4][2];
#pragma unroll
  for (int h = 0; h < 4; h++)
#pragma unroll
    for (int k0 = 0; k0 < 2; k0++)
      af[h][k0] = *(const bf16x8*)(za + h * 64 + k0 * 32 + quad * 8);
  int ibq = ib + quad * 4;
  float4 wi[4];
  float sqi[4][4];
#pragma unroll
  for (int reg = 0; reg < 4; reg++) {
    int i = ibq + reg;
    wi[reg] = wnode[b * 1408 + i];
#pragma unroll
    for (int h = 0; h < 4; h++) sqi[reg][h] = sq[(size_t)(b * 4 + h) * 1408 + i];
  }
#pragma unroll
  for (int js = 0; js < 4; js++) {
    int j = jt * 64 + js * 16 + l15;
    const unsigned short* zj = zb + (size_t)(b * 1408 + j) * 256;
    f32x4 acc[4];
#pragma unroll
    for (int h = 0; h < 4; h++) {
      bf16x8 b0 = *(const bf16x8*)(zj + h * 64 + quad * 8);
      bf16x8 b1f = *(const bf16x8*)(zj + h * 64 + 32 + quad * 8);
      f32x4 a = {0.f, 0.f, 0.f, 0.f};
      a = __builtin_amdgcn_mfma_f32_16x16x32_bf16(af[h][0], b0, a, 0, 0, 0);
      a = __builtin_amdgcn_mfma_f32_16x16x32_bf16(af[h][1], b1f, a, 0, 0, 0);
      acc[h] = a;
    }
    float sqj[4];
#pragma unroll
    for (int h = 0; h < 4; h++) sqj[h] = sq[(size_t)(b * 4 + h) * 1408 + j];
    float4 wj = wnode[b * 1408 + j];
    float adjv[4] = {0.f, 0.f, 0.f, 0.f};
#pragma unroll
    for (int h = 0; h < 4; h++) {
      const unsigned* bmh = bm + (size_t)(h * 16 + b) * 1408 * 44;
      unsigned wJ = bmh[(size_t)j * 44 + (ibq >> 5)];
#pragma unroll
      for (int reg = 0; reg < 4; reg++) {
        int i = ibq + reg;
        float d2 = sqi[reg][h] + sqj[h] - 2.f * acc[h][reg];
        d2 = fmaxf(d2, 0.f);
        float sim = exp2f(-d2 * c2h[h]);
        unsigned bi = bmh[(size_t)i * 44 + (j >> 5)] >> (j & 31);
        unsigned bj = wJ >> (i & 31);
        adjv[reg] += (((bi | bj) & 1u) != 0u) ? sim : 0.f;
      }
    }
#pragma unroll
    for (int reg = 0; reg < 4; reg++) {
      int i = ibq + reg;
      int chi = i >> 6, pi = i & 63, chj = j >> 6, pj = j & 63;
      float e0 = 0.5f * (wi[reg].x + wj.x);
      float e1 = 0.5f * (wi[reg].y + wj.y);
      float e2 = 0.5f * (wi[reg].z + wj.z);
      float a2 = 0.f;
      if (chi == chj) {
        int dp = pi - pj;
        if (dp == 1 || dp == -1) a2 += e0;
      }
      if (pi == pj && chadj[chi * 22 + chj] != 0.f) a2 += e1;
      float xw = (wi[reg].w * wj.w - thr) * 10.f;
      float pt = 1.f / (1.f + exp2f(-xw * 1.44269504088896f));
      a2 += pt * e2;
      out[(size_t)(b * 1408 + i) * 1408 + j] = 0.25f * adjv[reg] * a2;
    }
  }
}

// ---------------------------------------------------------------------------
extern "C" void kernel_launch(void* const* d_in, const int* in_sizes, int n_in,
                              void* d_out, int out_size, void* d_ws, size_t ws_size,
                              hipStream_t stream) {
  (void)in_sizes; (void)n_in; (void)out_size; (void)ws_size;
  const float* x = (const float*)d_in[0];
  const float* projw = (const float*)d_in[1];
  const float* gw = (const float*)d_in[2];
  const float* gb = (const float*)d_in[3];
  const float* w1 = (const float*)d_in[4];
  const float* b1 = (const float*)d_in[5];
  const float* w2 = (const float*)d_in[6];
  const float* b2 = (const float*)d_in[7];
  const float* thr = (const float*)d_in[8];
  const float* smask = (const float*)d_in[10];
  float* out = (float*)d_out;
  char* ws = (char*)d_ws;
  size_t off = 0;
  auto take = [&](size_t bytes) {
    char* p = ws + off;
    off += (bytes + 255) & ~(size_t)255;
    return p;
  };
  float* z = (float*)take((size_t)22528 * 256 * 4);
  unsigned short* zb = (unsigned short*)take((size_t)22528 * 256 * 2);
  unsigned short* zbl = (unsigned short*)take((size_t)22528 * 256 * 2);
  unsigned short* zbl2 = (unsigned short*)take((size_t)22528 * 256 * 2);
  float* h1 = (float*)take((size_t)22528 * 128 * 4);
  float* sq = (float*)take((size_t)16 * 4 * 1408 * 4);
  float4* wnode = (float4*)take((size_t)22528 * 16);
  unsigned* bm = (unsigned*)take((size_t)4 * 16 * 1408 * 44 * 4);
  float* chadj = (float*)take(484 * 4);
  double* sums = (double*)take(4 * 8);

  hipLaunchKernelGGL(k_init, dim3(1), dim3(512), 0, stream, smask, chadj, sums);
  hipLaunchKernelGGL(k_gemm_in, dim3(352, 6), dim3(256), 0, stream, x, projw, w1,
                     z, zb, zbl, zbl2, h1);
  hipLaunchKernelGGL(k_node, dim3(5632), dim3(256), 0, stream, x, z, h1, gw, gb,
                     b1, w2, b2, sq, wnode);
  hipLaunchKernelGGL(k_pass1, dim3(88, 16, 4), dim3(256), 0, stream, zb, zbl,
                     zbl2, sq, bm, sums);
  hipLaunchKernelGGL(k_final, dim3(22, 22, 16), dim3(256), 0, stream, zb, sq,
                     wnode, bm, sums, chadj, thr, out);
}

// Round 10
// 1211.320 us; speedup vs baseline: 1.0283x; 1.0283x over previous
//
#include <hip/hip_runtime.h>
#include <math.h>

typedef __attribute__((ext_vector_type(8))) short bf16x8;
typedef __attribute__((ext_vector_type(4))) float f32x4;

__device__ __forceinline__ float wsum64(float v) {
#pragma unroll
  for (int d = 32; d > 0; d >>= 1) v += __shfl_xor(v, d, 64);
  return v;
}

__device__ __forceinline__ unsigned short f2bf(float f) {
  unsigned u = __float_as_uint(f);
  u = (u + 0x7FFFu + ((u >> 16) & 1u)) >> 16;
  return (unsigned short)u;
}

__device__ __forceinline__ float bf2f(unsigned short h) {
  return __uint_as_float((unsigned)h << 16);
}

// ---------------- K0: init (chadj extract + zero mean-sums) ----------------
__global__ void k_init(const float* __restrict__ smask, float* __restrict__ chadj,
                       double* __restrict__ sums) {
  int t = threadIdx.x;
  if (t < 4) sums[t] = 0.0;
  if (t < 484) {
    int c1 = t / 22, c2 = t % 22;
    chadj[t] = smask[(size_t)(c1 * 64) * 1408 + (size_t)c2 * 64];
  }
}

// ---------------- A: input GEMM: z (fp32) + 3-term bf16 split + h1-pre ------
__global__ __launch_bounds__(256) void k_gemm_in(
    const float* __restrict__ x, const float* __restrict__ projw,
    const float* __restrict__ w1, float* __restrict__ z,
    unsigned short* __restrict__ zb, unsigned short* __restrict__ zbl,
    unsigned short* __restrict__ zbl2, float* __restrict__ h1) {
  __shared__ float xs[16][68];
  __shared__ float wsT[16][68];
  int n0 = blockIdx.x * 64;
  int o0 = blockIdx.y * 64;
  int tid = threadIdx.x;
  int tx = tid & 15, ty = tid >> 4;
  float acc[4][4];
#pragma unroll
  for (int i = 0; i < 4; i++)
#pragma unroll
    for (int j = 0; j < 4; j++) acc[i][j] = 0.f;
  for (int kc = 0; kc < 16; kc++) {
#pragma unroll
    for (int rep = 0; rep < 4; rep++) {
      int e = tid + rep * 256;
      int n = e >> 4, k = e & 15;
      xs[k][n] = x[(size_t)(n0 + n) * 256 + kc * 16 + k];
      int row = o0 + n;
      wsT[k][n] = (row < 256) ? projw[(size_t)row * 256 + kc * 16 + k]
                              : w1[(size_t)(row - 256) * 256 + kc * 16 + k];
    }
    __syncthreads();
#pragma unroll
    for (int k = 0; k < 16; k++) {
      float4 a4 = *(const float4*)&xs[k][4 * ty];
      float4 w4 = *(const float4*)&wsT[k][4 * tx];
      float ar[4] = {a4.x, a4.y, a4.z, a4.w};
      float wr[4] = {w4.x, w4.y, w4.z, w4.w};
#pragma unroll
      for (int i = 0; i < 4; i++)
#pragma unroll
        for (int j = 0; j < 4; j++) acc[i][j] = fmaf(ar[i], wr[j], acc[i][j]);
    }
    __syncthreads();
  }
  if (blockIdx.y >= 4) {
#pragma unroll
    for (int i = 0; i < 4; i++) {
      size_t base = (size_t)(n0 + 4 * ty + i) * 128 + (o0 - 256) + 4 * tx;
      float4 t;
      t.x = acc[i][0]; t.y = acc[i][1]; t.z = acc[i][2]; t.w = acc[i][3];
      *(float4*)&h1[base] = t;
    }
  } else {
#pragma unroll
    for (int i = 0; i < 4; i++) {
      size_t base = (size_t)(n0 + 4 * ty + i) * 256 + o0 + 4 * tx;
      float4 t;
      t.x = acc[i][0]; t.y = acc[i][1]; t.z = acc[i][2]; t.w = acc[i][3];
      *(float4*)&z[base] = t;
      unsigned short hh[4], ll[4], mm[4];
#pragma unroll
      for (int j = 0; j < 4; j++) {
        float xv = acc[i][j];
        unsigned short h0 = f2bf(xv);
        float r1 = xv - bf2f(h0);
        unsigned short h1v = f2bf(r1);
        float r2 = r1 - bf2f(h1v);
        unsigned short h2 = f2bf(r2);
        hh[j] = h0; ll[j] = h1v; mm[j] = h2;
      }
      uint2 u2;
      u2.x = (unsigned)hh[0] | ((unsigned)hh[1] << 16);
      u2.y = (unsigned)hh[2] | ((unsigned)hh[3] << 16);
      *(uint2*)(zb + base) = u2;
      u2.x = (unsigned)ll[0] | ((unsigned)ll[1] << 16);
      u2.y = (unsigned)ll[2] | ((unsigned)ll[3] << 16);
      *(uint2*)(zbl + base) = u2;
      u2.x = (unsigned)mm[0] | ((unsigned)mm[1] << 16);
      u2.y = (unsigned)mm[2] | ((unsigned)mm[3] << 16);
      *(uint2*)(zbl2 + base) = u2;
    }
  }
}

// ---------------- B: per-node: sq per head, score (exact gelu), top-p gate --
__global__ __launch_bounds__(256) void k_node(
    const float* __restrict__ x, const float* __restrict__ z,
    const float* __restrict__ h1, const float* __restrict__ gw,
    const float* __restrict__ gb, const float* __restrict__ b1,
    const float* __restrict__ w2, const float* __restrict__ b2v,
    float* __restrict__ sq, float4* __restrict__ wnode) {
  int tid = threadIdx.x;
  int w = tid >> 6, lane = tid & 63;
  int node = blockIdx.x * 4 + w;
  int b = node / 1408, n = node % 1408;
  const float* zr = z + (size_t)node * 256;
  const float* xr = x + (size_t)node * 256;
#pragma unroll
  for (int c = 0; c < 4; c++) {
    float val = zr[c * 64 + lane];
    float s = wsum64(val * val);
    if (lane == 0) sq[(size_t)(b * 4 + c) * 1408 + n] = s;
  }
  float gl[3];
#pragma unroll
  for (int f = 0; f < 3; f++) {
    float p = 0.f;
#pragma unroll
    for (int c = 0; c < 4; c++)
      p = fmaf(xr[c * 64 + lane], gw[f * 256 + c * 64 + lane], p);
    gl[f] = wsum64(p) + gb[f];
  }
  const float* hr = h1 + (size_t)node * 128;
  float ps = 0.f;
#pragma unroll
  for (int c = 0; c < 2; c++) {
    float t = hr[c * 64 + lane] + b1[c * 64 + lane];
    float g = 0.5f * t * (1.f + erff(t * 0.7071067811865475f));
    ps = fmaf(g, w2[c * 64 + lane], ps);
  }
  float sc = wsum64(ps) + b2v[0];
  sc = 1.f / (1.f + expf(-sc));
  float mx = fmaxf(gl[0], fmaxf(gl[1], gl[2]));
  float ex[3];
  float esum = 0.f;
#pragma unroll
  for (int f = 0; f < 3; f++) { ex[f] = expf(gl[f] - mx); esum += ex[f]; }
  float p3[3];
#pragma unroll
  for (int f = 0; f < 3; f++) p3[f] = ex[f] / esum;
  int rk[3];
#pragma unroll
  for (int f = 0; f < 3; f++) {
    int r = 0;
#pragma unroll
    for (int g = 0; g < 3; g++)
      r += ((p3[g] > p3[f]) || (p3[g] == p3[f] && g < f)) ? 1 : 0;
    rk[f] = r;
  }
  float sp[3]; int oi[3];
#pragma unroll
  for (int f = 0; f < 3; f++) { sp[rk[f]] = p3[f]; oi[rk[f]] = f; }
  bool k1 = sp[0] < 0.85f;
  bool k2 = (sp[0] + sp[1]) < 0.85f;
  float wv[3];
  wv[oi[0]] = sp[0];
  wv[oi[1]] = k1 ? sp[1] : 0.f;
  wv[oi[2]] = k2 ? sp[2] : 0.f;
  float inv = 1.f / (wv[0] + wv[1] + wv[2] + 1e-8f);
  if (lane == 0) wnode[node] = make_float4(wv[0] * inv, wv[1] * inv, wv[2] * inv, sc);
}

// ---------------- P1: MFMA distances, single pass + reg keys -> bitmap ------
// grid (88,16,4); block 256 = 4 waves; wave w owns j-tiles w*22..w*22+21.
// R9 lessons: MFMA-d passed refcheck (no top-k flips), but 12-deep dep chain
// + full phase-2 recompute left MfmaUtil at 9%. Here: ONE MFMA pass (3
// independent 4-deep acc chains), 8-bit keys (d*2, 256 bins) packed in 22
// u32 registers; phase 2 derives bitmap ballots + candidate membership from
// registers (zero recompute). Exact d only for ~28 candidates/row via
// scalar fp32 dots from z (self-consistent exact set -> exact rank).
__global__ __launch_bounds__(256, 2) void k_pass1(
    const unsigned short* __restrict__ zb, const unsigned short* __restrict__ zbl,
    const unsigned short* __restrict__ zbl2, const float* __restrict__ z,
    const float* __restrict__ sq, unsigned* __restrict__ bm,
    double* __restrict__ sums) {
  __shared__ unsigned hist[8][264];   // 256 bins, rows 2r,2r+1 packed u16
  __shared__ float candD[16][128];
  __shared__ unsigned short candJ[16][128];
  __shared__ unsigned candCnt[16];
  __shared__ int tbinS[16], rstarS[16];
  __shared__ unsigned bmL[16][44];
  __shared__ float srowL[16];
  int b = blockIdx.y, h = blockIdx.z;
  int i0 = blockIdx.x * 16;
  int tid = threadIdx.x, w = tid >> 6, lane = tid & 63;
  int quad = lane >> 4, l15 = lane & 15;
  const float* sqh = sq + (size_t)(b * 4 + h) * 1408;
  {
    unsigned* hf = &hist[0][0];
    for (int u = tid; u < 8 * 264; u += 256) hf[u] = 0u;
  }
  if (tid < 16) { candCnt[tid] = 0u; srowL[tid] = sqh[i0 + tid]; }
  __syncthreads();

  // A fragments (rows i0..i0+15), 3 split terms x 2 K-halves
  size_t abase = ((size_t)(b * 1408 + i0 + l15)) * 256 + h * 64;
  bf16x8 ah[2], al[2], am[2];
#pragma unroll
  for (int k0 = 0; k0 < 2; k0++) {
    ah[k0] = *(const bf16x8*)(zb + abase + k0 * 32 + quad * 8);
    al[k0] = *(const bf16x8*)(zbl + abase + k0 * 32 + quad * 8);
    am[k0] = *(const bf16x8*)(zbl2 + abase + k0 * 32 + quad * 8);
  }

  // ---- single MFMA pass: d -> ssum + packed 8-bit keys in registers ----
  float ssum = 0.f;
  unsigned keys[22];
#pragma unroll
  for (int t = 0; t < 22; t++) {
    int tile = w * 22 + t;
    size_t jbb = ((size_t)(b * 1408 + tile * 16 + l15)) * 256 + h * 64;
    bf16x8 bh0 = *(const bf16x8*)(zb + jbb + quad * 8);
    bf16x8 bh1 = *(const bf16x8*)(zb + jbb + 32 + quad * 8);
    bf16x8 bl0 = *(const bf16x8*)(zbl + jbb + quad * 8);
    bf16x8 bl1 = *(const bf16x8*)(zbl + jbb + 32 + quad * 8);
    bf16x8 bm0 = *(const bf16x8*)(zbl2 + jbb + quad * 8);
    bf16x8 bm1 = *(const bf16x8*)(zbl2 + jbb + 32 + quad * 8);
    f32x4 a0 = {0.f, 0.f, 0.f, 0.f};
    f32x4 a1 = {0.f, 0.f, 0.f, 0.f};
    f32x4 a2 = {0.f, 0.f, 0.f, 0.f};
    // 3 independent 4-deep chains
    a0 = __builtin_amdgcn_mfma_f32_16x16x32_bf16(ah[0], bh0, a0, 0, 0, 0);
    a1 = __builtin_amdgcn_mfma_f32_16x16x32_bf16(al[0], bh0, a1, 0, 0, 0);
    a2 = __builtin_amdgcn_mfma_f32_16x16x32_bf16(am[0], bh0, a2, 0, 0, 0);
    a0 = __builtin_amdgcn_mfma_f32_16x16x32_bf16(ah[1], bh1, a0, 0, 0, 0);
    a1 = __builtin_amdgcn_mfma_f32_16x16x32_bf16(al[1], bh1, a1, 0, 0, 0);
    a2 = __builtin_amdgcn_mfma_f32_16x16x32_bf16(am[1], bh1, a2, 0, 0, 0);
    a0 = __builtin_amdgcn_mfma_f32_16x16x32_bf16(ah[0], bl0, a0, 0, 0, 0);
    a1 = __builtin_amdgcn_mfma_f32_16x16x32_bf16(al[0], bl0, a1, 0, 0, 0);
    a2 = __builtin_amdgcn_mfma_f32_16x16x32_bf16(ah[0], bm0, a2, 0, 0, 0);
    a0 = __builtin_amdgcn_mfma_f32_16x16x32_bf16(ah[1], bl1, a0, 0, 0, 0);
    a1 = __builtin_amdgcn_mfma_f32_16x16x32_bf16(al[1], bl1, a1, 0, 0, 0);
    a2 = __builtin_amdgcn_mfma_f32_16x16x32_bf16(ah[1], bm1, a2, 0, 0, 0);
    float sqjv = sqh[tile * 16 + l15];
    unsigned kw = 0;
#pragma unroll
    for (int reg = 0; reg < 4; reg++) {
      float accv = a0[reg] + a1[reg] + a2[reg];
      float d = srowL[quad * 4 + reg] + sqjv - 2.f * accv;
      d = fmaxf(d, 0.f);
      ssum += sqrtf(d);
      unsigned key = (unsigned)fminf(d * 2.0f, 255.0f);
      kw |= key << (8 * reg);
    }
    keys[t] = kw;
  }

  // ---- hist fill from keys ----
#pragma unroll
  for (int t = 0; t < 22; t++) {
    unsigned kw = keys[t];
#pragma unroll
    for (int reg = 0; reg < 4; reg++) {
      unsigned key = (kw >> (8 * reg)) & 255u;
      int row = quad * 4 + reg;
      atomicAdd(&hist[row >> 1][key + (key >> 6)], 1u << ((row & 1) * 16));
    }
  }
  __syncthreads();

  // ---- scan (256 bins): wave w handles rows 4w..4w+3 ----
#pragma unroll 1
  for (int q = 0; q < 4; q++) {
    int r = 4 * w + q;
    int sh = (r & 1) * 16;
    const unsigned* hrow = hist[r >> 1];
    unsigned partial = 0;
#pragma unroll
    for (int u = 0; u < 4; u++) {
      int bin = 4 * lane + u;
      partial += (hrow[bin + (bin >> 6)] >> sh) & 0xffffu;
    }
    unsigned inc = partial;
#pragma unroll
    for (int d = 1; d < 64; d <<= 1) {
      unsigned u2 = __shfl_up(inc, d, 64);
      if (lane >= d) inc += u2;
    }
    unsigned long long mk = __ballot(inc >= 211u);
    int Ls = __ffsll(mk) - 1;
    unsigned cbefore = (Ls > 0) ? (unsigned)__shfl((int)inc, Ls - 1, 64) : 0u;
    int tb = -1;
    unsigned run = cbefore, cbelow = cbefore;
#pragma unroll
    for (int u = 0; u < 4; u++) {
      int bin = 4 * Ls + u;
      unsigned c = (hrow[bin + (bin >> 6)] >> sh) & 0xffffu;
      if (tb < 0) {
        if (run + c >= 211u) { tb = bin; cbelow = run; }
        run += c;
      }
    }
    if (lane == 0) { tbinS[r] = tb; rstarS[r] = 211 - (int)cbelow; }
  }
  __syncthreads();

  // ---- phase 2 (from registers): provisional bits + candidate collect ----
#pragma unroll
  for (int t = 0; t < 22; t++) {
    int tile = w * 22 + t;
    unsigned kw = keys[t];
#pragma unroll
    for (int reg = 0; reg < 4; reg++) {
      unsigned key = (kw >> (8 * reg)) & 255u;
      int row = quad * 4 + reg;
      int tb = tbinS[row];
      unsigned long long bl = __ballot((int)key < tb);
      if (l15 == 0)
        ((unsigned short*)&bmL[row][0])[tile] = (unsigned short)(bl >> (quad * 16));
      if ((int)key == tb) {
        unsigned id = atomicAdd(&candCnt[row], 1u);
        if (id < 128u) candJ[row][id] = (unsigned short)(tile * 16 + l15);
      }
    }
  }
  __syncthreads();

  // ---- exact d for candidates: scalar fp32 dot from z ----
  const float* zbh = z + ((size_t)(b * 1408)) * 256 + h * 64;
  for (int u = tid; u < 16 * 128; u += 256) {
    int row = u >> 7, ci = u & 127;
    unsigned cnt = candCnt[row];
    if (cnt > 128u) cnt = 128u;
    if (ci < (int)cnt) {
      int j = candJ[row][ci];
      const float* zi = zbh + (size_t)(i0 + row) * 256;
      const float* zj = zbh + (size_t)j * 256;
      float dot = 0.f;
#pragma unroll
      for (int k = 0; k < 64; k++) dot = fmaf(zi[k], zj[k], dot);
      float d = srowL[row] + sqh[j] - 2.f * dot;
      candD[row][ci] = fmaxf(d, 0.f);
    }
  }
  __syncthreads();

  // ---- rank within threshold bin + boundary bits: wave w rows 4w..4w+3 ----
#pragma unroll 1
  for (int q = 0; q < 4; q++) {
    int row = 4 * w + q;
    int rstar = rstarS[row];
    unsigned craw = candCnt[row];
    int cnt = (craw > 128u) ? 128 : (int)craw;
    float t2l = INFINITY;
    for (int base = 0; base < cnt; base += 64) {
      int ci = base + lane;
      if (ci < cnt) {
        float xm = candD[row][ci];
        int below = 0, eq = 0;
        for (int m = 0; m < cnt; m++) {
          float y = candD[row][m];
          below += (y < xm) ? 1 : 0;
          eq += (y == xm) ? 1 : 0;
        }
        if (below < rstar && rstar <= below + eq) t2l = fminf(t2l, xm);
      }
    }
#pragma unroll
    for (int dd = 32; dd > 0; dd >>= 1) t2l = fminf(t2l, __shfl_xor(t2l, dd, 64));
    // boundary bits (same wave, t2l uniform across lanes)
    for (int ci = lane; ci < cnt; ci += 64) {
      if (candD[row][ci] <= t2l) {
        int j = candJ[row][ci];
        atomicOr(&bmL[row][j >> 5], 1u << (j & 31));
      }
    }
  }
  __syncthreads();

  // ---- writeout ----
  for (int u = tid; u < 16 * 44; u += 256) {
    int row = u / 44, wd = u % 44;
    bm[((size_t)((h * 16 + b) * 1408 + i0 + row)) * 44 + wd] = bmL[row][wd];
  }
  ssum = wsum64(ssum);
  if (lane == 0) atomicAdd(&sums[h], (double)ssum);
}

// ---------------- E: bf16-MFMA recompute + fused epilogue -> out ------------
__global__ __launch_bounds__(256) void k_final(
    const unsigned short* __restrict__ zb, const float* __restrict__ sq,
    const float4* __restrict__ wnode, const unsigned* __restrict__ bm,
    const double* __restrict__ sums, const float* __restrict__ chadj,
    const float* __restrict__ thrp, float* __restrict__ out) {
  int it = blockIdx.x, jt = blockIdx.y, b = blockIdx.z;
  int tid = threadIdx.x, wv = tid >> 6, lane = tid & 63;
  int quad = lane >> 4, l15 = lane & 15;
  float c2h[4];
#pragma unroll
  for (int h = 0; h < 4; h++) {
    double mu = sums[h] * (1.0 / (16.0 * 1408.0 * 1408.0));
    c2h[h] = (float)(1.0 / (2.0 * mu * mu + 1e-8)) * 1.44269504088896f;
  }
  float thr = thrp[0];
  int ib = it * 64 + wv * 16;
  const unsigned short* za = zb + (size_t)(b * 1408 + ib + l15) * 256;
  bf16x8 af[4][2];
#pragma unroll
  for (int h = 0; h < 4; h++)
#pragma unroll
    for (int k0 = 0; k0 < 2; k0++)
      af[h][k0] = *(const bf16x8*)(za + h * 64 + k0 * 32 + quad * 8);
  int ibq = ib + quad * 4;
  float4 wi[4];
  float sqi[4][4];
#pragma unroll
  for (int reg = 0; reg < 4; reg++) {
    int i = ibq + reg;
    wi[reg] = wnode[b * 1408 + i];
#pragma unroll
    for (int h = 0; h < 4; h++) sqi[reg][h] = sq[(size_t)(b * 4 + h) * 1408 + i];
  }
#pragma unroll
  for (int js = 0; js < 4; js++) {
    int j = jt * 64 + js * 16 + l15;
    const unsigned short* zj = zb + (size_t)(b * 1408 + j) * 256;
    f32x4 acc[4];
#pragma unroll
    for (int h = 0; h < 4; h++) {
      bf16x8 b0 = *(const bf16x8*)(zj + h * 64 + quad * 8);
      bf16x8 b1f = *(const bf16x8*)(zj + h * 64 + 32 + quad * 8);
      f32x4 a = {0.f, 0.f, 0.f, 0.f};
      a = __builtin_amdgcn_mfma_f32_16x16x32_bf16(af[h][0], b0, a, 0, 0, 0);
      a = __builtin_amdgcn_mfma_f32_16x16x32_bf16(af[h][1], b1f, a, 0, 0, 0);
      acc[h] = a;
    }
    float sqj[4];
#pragma unroll
    for (int h = 0; h < 4; h++) sqj[h] = sq[(size_t)(b * 4 + h) * 1408 + j];
    float4 wj = wnode[b * 1408 + j];
    float adjv[4] = {0.f, 0.f, 0.f, 0.f};
#pragma unroll
    for (int h = 0; h < 4; h++) {
      const unsigned* bmh = bm + (size_t)(h * 16 + b) * 1408 * 44;
      unsigned wJ = bmh[(size_t)j * 44 + (ibq >> 5)];
#pragma unroll
      for (int reg = 0; reg < 4; reg++) {
        int i = ibq + reg;
        float d2 = sqi[reg][h] + sqj[h] - 2.f * acc[h][reg];
        d2 = fmaxf(d2, 0.f);
        float sim = exp2f(-d2 * c2h[h]);
        unsigned bi = bmh[(size_t)i * 44 + (j >> 5)] >> (j & 31);
        unsigned bj = wJ >> (i & 31);
        adjv[reg] += (((bi | bj) & 1u) != 0u) ? sim : 0.f;
      }
    }
#pragma unroll
    for (int reg = 0; reg < 4; reg++) {
      int i = ibq + reg;
      int chi = i >> 6, pi = i & 63, chj = j >> 6, pj = j & 63;
      float e0 = 0.5f * (wi[reg].x + wj.x);
      float e1 = 0.5f * (wi[reg].y + wj.y);
      float e2 = 0.5f * (wi[reg].z + wj.z);
      float a2 = 0.f;
      if (chi == chj) {
        int dp = pi - pj;
        if (dp == 1 || dp == -1) a2 += e0;
      }
      if (pi == pj && chadj[chi * 22 + chj] != 0.f) a2 += e1;
      float xw = (wi[reg].w * wj.w - thr) * 10.f;
      float pt = 1.f / (1.f + exp2f(-xw * 1.44269504088896f));
      a2 += pt * e2;
      out[(size_t)(b * 1408 + i) * 1408 + j] = 0.25f * adjv[reg] * a2;
    }
  }
}

// ---------------------------------------------------------------------------
extern "C" void kernel_launch(void* const* d_in, const int* in_sizes, int n_in,
                              void* d_out, int out_size, void* d_ws, size_t ws_size,
                              hipStream_t stream) {
  (void)in_sizes; (void)n_in; (void)out_size; (void)ws_size;
  const float* x = (const float*)d_in[0];
  const float* projw = (const float*)d_in[1];
  const float* gw = (const float*)d_in[2];
  const float* gb = (const float*)d_in[3];
  const float* w1 = (const float*)d_in[4];
  const float* b1 = (const float*)d_in[5];
  const float* w2 = (const float*)d_in[6];
  const float* b2 = (const float*)d_in[7];
  const float* thr = (const float*)d_in[8];
  const float* smask = (const float*)d_in[10];
  float* out = (float*)d_out;
  char* ws = (char*)d_ws;
  size_t off = 0;
  auto take = [&](size_t bytes) {
    char* p = ws + off;
    off += (bytes + 255) & ~(size_t)255;
    return p;
  };
  float* z = (float*)take((size_t)22528 * 256 * 4);
  unsigned short* zb = (unsigned short*)take((size_t)22528 * 256 * 2);
  unsigned short* zbl = (unsigned short*)take((size_t)22528 * 256 * 2);
  unsigned short* zbl2 = (unsigned short*)take((size_t)22528 * 256 * 2);
  float* h1 = (float*)take((size_t)22528 * 128 * 4);
  float* sq = (float*)take((size_t)16 * 4 * 1408 * 4);
  float4* wnode = (float4*)take((size_t)22528 * 16);
  unsigned* bm = (unsigned*)take((size_t)4 * 16 * 1408 * 44 * 4);
  float* chadj = (float*)take(484 * 4);
  double* sums = (double*)take(4 * 8);

  hipLaunchKernelGGL(k_init, dim3(1), dim3(512), 0, stream, smask, chadj, sums);
  hipLaunchKernelGGL(k_gemm_in, dim3(352, 6), dim3(256), 0, stream, x, projw, w1,
                     z, zb, zbl, zbl2, h1);
  hipLaunchKernelGGL(k_node, dim3(5632), dim3(256), 0, stream, x, z, h1, gw, gb,
                     b1, w2, b2, sq, wnode);
  hipLaunchKernelGGL(k_pass1, dim3(88, 16, 4), dim3(256), 0, stream, zb, zbl,
                     zbl2, z, sq, bm, sums);
  hipLaunchKernelGGL(k_final, dim3(22, 22, 16), dim3(256), 0, stream, zb, sq,
                     wnode, bm, sums, chadj, thr, out);
}